// Round 15
// baseline (175.578 us; speedup 1.0000x reference)
//
#include <hip/hip_runtime.h>

#define NN 100000
#define NE 1600000
#define D 64
#define NB 128                                 // binning blocks
#define EPB (NE / NB)                          // 12500 edges per bin block
#define BROWS 64                               // rows per bucket
#define NBK ((NN + BROWS - 1) / BROWS)         // 1563 buckets
#define NH (NBK * NB)                          // 200064 hist entries
#define SCAN_BLK 1024
#define NSB ((NH + SCAN_BLK - 1) / SCAN_BLK)   // 196
#define CAP 1536                               // per-bucket capacity (16 sigma)

// ---------------- ws layout (bytes), total 39,201,792 (proven) -------------
// agg16  : [0, 12800000)             NN*D bf16
// bh     : [12800000, +800768)       NH int (hist -> in-place exclusive scan)
// bsum   : [13600768, +1024)         NSB int
// coarse : [13601792, +12800000)     NE int2 ((rowlocal<<17)|col, val-bits)
// feat16 : [26401792, +12800000)     NN*D bf16
static constexpr size_t OFF_AGG16  = 0;
static constexpr size_t OFF_BH     = 12800000;
static constexpr size_t OFF_BS     = 13600768;
static constexpr size_t OFF_COARSE = 13601792;
static constexpr size_t OFF_F16    = 26401792;

__device__ __forceinline__ unsigned short f32_to_bf16_rn(float x) {
    unsigned int u = __float_as_uint(x);
    u += 0x7FFFu + ((u >> 16) & 1u);  // round-to-nearest-even
    return (unsigned short)(u >> 16);
}
__device__ __forceinline__ float bf16_to_f32(unsigned int lo16) {
    return __uint_as_float(lo16 << 16);
}

// 0) feat f32 -> bf16 (8 elems/thread)
__global__ __launch_bounds__(256) void conv_k(const float* __restrict__ feat,
                                              unsigned short* __restrict__ feat16) {
    int i = blockIdx.x * blockDim.x + threadIdx.x;
    if (i >= NN * D / 8) return;
    const float4 f0 = *reinterpret_cast<const float4*>(&feat[i * 8]);
    const float4 f1 = *reinterpret_cast<const float4*>(&feat[i * 8 + 4]);
    uint4 o;
    o.x = f32_to_bf16_rn(f0.x) | ((unsigned int)f32_to_bf16_rn(f0.y) << 16);
    o.y = f32_to_bf16_rn(f0.z) | ((unsigned int)f32_to_bf16_rn(f0.w) << 16);
    o.z = f32_to_bf16_rn(f1.x) | ((unsigned int)f32_to_bf16_rn(f1.y) << 16);
    o.w = f32_to_bf16_rn(f1.z) | ((unsigned int)f32_to_bf16_rn(f1.w) << 16);
    *reinterpret_cast<uint4*>(&feat16[i * 8]) = o;
}

// 1) per-(bucket, block) histogram. bh layout bucket-major: bh[b*NB + blk]
__global__ __launch_bounds__(256) void bhist_k(const int* __restrict__ rows,
                                               int* __restrict__ bh) {
    __shared__ int h[NBK];
    for (int i = threadIdx.x; i < NBK; i += 256) h[i] = 0;
    __syncthreads();
    const int e0 = blockIdx.x * EPB;
    for (int e = e0 + threadIdx.x; e < e0 + EPB; e += 256)
        atomicAdd(&h[rows[e] >> 6], 1);
    __syncthreads();
    for (int i = threadIdx.x; i < NBK; i += 256) bh[i * NB + blockIdx.x] = h[i];
}

// 2a) per-1024-block exclusive scan over bh, IN-PLACE; block sums out
__global__ __launch_bounds__(256) void scan1_k(int* __restrict__ a,
                                               int* __restrict__ bsum) {
    __shared__ int tsum[256];
    const int base = blockIdx.x * SCAN_BLK + threadIdx.x * 4;
    int v[4];
    int s = 0;
#pragma unroll
    for (int i = 0; i < 4; ++i) {
        int idx = base + i;
        v[i] = (idx < NH) ? a[idx] : 0;
        s += v[i];
    }
    tsum[threadIdx.x] = s;
    __syncthreads();
    int x = s;
    for (int off = 1; off < 256; off <<= 1) {
        int y = (threadIdx.x >= off) ? tsum[threadIdx.x - off] : 0;
        __syncthreads();
        x += y;
        tsum[threadIdx.x] = x;
        __syncthreads();
    }
    int run = x - s;
#pragma unroll
    for (int i = 0; i < 4; ++i) {
        int idx = base + i;
        if (idx < NH) a[idx] = run;
        run += v[i];
    }
    if (threadIdx.x == 255) bsum[blockIdx.x] = x;
}

// 2b) exclusive scan of NSB (=196) block sums
__global__ void scan2_k(int* __restrict__ bsum) {
    __shared__ int s[256];
    int i = threadIdx.x;
    int v = (i < NSB) ? bsum[i] : 0;
    s[i] = v;
    __syncthreads();
    int x = v;
    for (int off = 1; off < 256; off <<= 1) {
        int y = (i >= off) ? s[i - off] : 0;
        __syncthreads();
        x += y;
        s[i] = x;
        __syncthreads();
    }
    if (i < NSB) bsum[i] = x - v;  // exclusive
}

// 2c) add block offsets
__global__ __launch_bounds__(256) void scan3_k(int* __restrict__ a,
                                               const int* __restrict__ bsum) {
    int i = blockIdx.x * blockDim.x + threadIdx.x;
    if (i < NH) a[i] += bsum[i >> 10];
}

// 3) bin edges into coarse buckets at exact (block,bucket) offsets.
__global__ __launch_bounds__(256) void bin_k(const int* __restrict__ rows,
                                             const int* __restrict__ cols,
                                             const float* __restrict__ vals,
                                             const int* __restrict__ bh,
                                             int2* __restrict__ coarse) {
    __shared__ int cur[NBK];
    for (int i = threadIdx.x; i < NBK; i += 256) cur[i] = 0;
    __syncthreads();
    const int e0 = blockIdx.x * EPB;
    for (int e = e0 + threadIdx.x; e < e0 + EPB; e += 256) {
        int r = rows[e];
        int b = r >> 6;
        int pos = atomicAdd(&cur[b], 1);
        coarse[bh[b * NB + blockIdx.x] + pos] =
            make_int2(((r & 63) << 17) | cols[e], __float_as_int(vals[e]));
    }
}

// 4) per-bucket LDS counting-sort + register-accumulate gather.
//    Block b owns rows [b*64, b*64+64). LDS 12.8KB -> 8 blocks/CU (thread-
//    limited), fixing R14's 26% occupancy. Wave wv gathers rows
//    [wv*16, wv*16+16), 8 edges in flight, acc in registers, dense row write.
__global__ __launch_bounds__(256) void bgather_k(const int* __restrict__ bh,
                                                 const int2* __restrict__ coarse,
                                                 const unsigned short* __restrict__ feat16,
                                                 unsigned short* __restrict__ agg16) {
    __shared__ int2 se[CAP];
    __shared__ int hist[BROWS];    // counts -> cursor base
    __shared__ int rsl[BROWS];     // inclusive scan
    const int b = blockIdx.x;
    const int start = bh[b * NB];
    const int end = (b == NBK - 1) ? NE : bh[(b + 1) * NB];
    int n = end - start;
    if (n > CAP) n = CAP;  // 16-sigma headroom; never expected

    const int tid = threadIdx.x;
    if (tid < BROWS) hist[tid] = 0;
    __syncthreads();
    for (int i = tid; i < n; i += 256)
        atomicAdd(&hist[((unsigned)coarse[start + i].x) >> 17], 1);
    __syncthreads();
    if (tid < BROWS) rsl[tid] = hist[tid];
    __syncthreads();
    for (int off = 1; off < BROWS; off <<= 1) {
        int y = 0;
        if (tid < BROWS && tid >= off) y = rsl[tid - off];
        __syncthreads();
        if (tid < BROWS) rsl[tid] += y;
        __syncthreads();
    }
    if (tid < BROWS) hist[tid] = rsl[tid] - hist[tid];  // cursor = row start
    __syncthreads();
    for (int i = tid; i < n; i += 256) {
        int2 ev = coarse[start + i];
        int p = atomicAdd(&hist[((unsigned)ev.x) >> 17], 1);
        se[p] = ev;
    }
    __syncthreads();

    const int lane = tid & 63;
    const int wv = tid >> 6;
    const int g = lane >> 3;
    const int t = lane & 7;
    const int rowbase = b * BROWS;

    for (int rl = wv * 16; rl < wv * 16 + 16; ++rl) {
        const int r0 = (rl == 0) ? 0 : rsl[rl - 1];
        const int r1 = rsl[rl];
        float acc[8];
#pragma unroll
        for (int k = 0; k < 8; ++k) acc[k] = 0.f;
        for (int base2 = r0; base2 < r1; base2 += 8) {
            int m = r1 - base2;
            if (m > 8) m = 8;
            int2 ev = se[base2 + (g < m ? g : 0)];   // 8-lane broadcast per group
            float vj = (g < m) ? __int_as_float(ev.y) : 0.f;
            int cj = ev.x & 0x1FFFF;
            const uint4 f =
                *reinterpret_cast<const uint4*>(&feat16[(size_t)cj * D + (t << 3)]);
            acc[0] += vj * bf16_to_f32(f.x & 0xffffu);
            acc[1] += vj * bf16_to_f32(f.x >> 16);
            acc[2] += vj * bf16_to_f32(f.y & 0xffffu);
            acc[3] += vj * bf16_to_f32(f.y >> 16);
            acc[4] += vj * bf16_to_f32(f.z & 0xffffu);
            acc[5] += vj * bf16_to_f32(f.z >> 16);
            acc[6] += vj * bf16_to_f32(f.w & 0xffffu);
            acc[7] += vj * bf16_to_f32(f.w >> 16);
        }
#pragma unroll
        for (int off = 8; off <= 32; off <<= 1) {
#pragma unroll
            for (int k = 0; k < 8; ++k) acc[k] += __shfl_xor(acc[k], off);
        }
        const int r = rowbase + rl;
        if (lane < 8 && r < NN) {
            uint4 o;
            o.x = f32_to_bf16_rn(acc[0]) | ((unsigned int)f32_to_bf16_rn(acc[1]) << 16);
            o.y = f32_to_bf16_rn(acc[2]) | ((unsigned int)f32_to_bf16_rn(acc[3]) << 16);
            o.z = f32_to_bf16_rn(acc[4]) | ((unsigned int)f32_to_bf16_rn(acc[5]) << 16);
            o.w = f32_to_bf16_rn(acc[6]) | ((unsigned int)f32_to_bf16_rn(acc[7]) << 16);
            *reinterpret_cast<uint4*>(&agg16[(size_t)r * D + (t << 3)]) = o;
        }
    }
}

// 5) out = leaky(agg@W1+b1) + leaky((agg*feat)@W2+b2); agg in bf16
__global__ __launch_bounds__(256) void mlp_k(const unsigned short* __restrict__ agg16,
                                             const float* __restrict__ feat,
                                             const float* __restrict__ W1,
                                             const float* __restrict__ b1,
                                             const float* __restrict__ W2,
                                             const float* __restrict__ b2,
                                             float* __restrict__ out) {
    __shared__ float W1s[64 * 64];
    __shared__ float W2s[64 * 64];
    __shared__ float b1s[64], b2s[64];
    __shared__ float As[64][65];
    __shared__ float Ms[64][65];

    for (int i = threadIdx.x; i < 4096; i += 256) {
        W1s[i] = W1[i];
        W2s[i] = W2[i];
    }
    if (threadIdx.x < 64) {
        b1s[threadIdx.x] = b1[threadIdx.x];
        b2s[threadIdx.x] = b2[threadIdx.x];
    }

    const int wv = threadIdx.x >> 6;
    const int lane = threadIdx.x & 63;
    const int ntiles = (NN + 63) / 64;

    for (int t = blockIdx.x; t < ntiles; t += gridDim.x) {
        const int base = t * 64;
        __syncthreads();
        for (int i = threadIdx.x; i < 512; i += 256) {
            int row = i >> 3;
            int sg = i & 7;
            int n = base + row;
            uint4 a16 = make_uint4(0, 0, 0, 0);
            float4 f0 = make_float4(0.f, 0.f, 0.f, 0.f);
            float4 f1 = make_float4(0.f, 0.f, 0.f, 0.f);
            if (n < NN) {
                a16 = *reinterpret_cast<const uint4*>(&agg16[(size_t)n * D + sg * 8]);
                f0 = *reinterpret_cast<const float4*>(&feat[(size_t)n * D + sg * 8]);
                f1 = *reinterpret_cast<const float4*>(&feat[(size_t)n * D + sg * 8 + 4]);
            }
            float a[8];
            a[0] = bf16_to_f32(a16.x & 0xffffu);
            a[1] = bf16_to_f32(a16.x >> 16);
            a[2] = bf16_to_f32(a16.y & 0xffffu);
            a[3] = bf16_to_f32(a16.y >> 16);
            a[4] = bf16_to_f32(a16.z & 0xffffu);
            a[5] = bf16_to_f32(a16.z >> 16);
            a[6] = bf16_to_f32(a16.w & 0xffffu);
            a[7] = bf16_to_f32(a16.w >> 16);
            float f[8] = {f0.x, f0.y, f0.z, f0.w, f1.x, f1.y, f1.z, f1.w};
#pragma unroll
            for (int k = 0; k < 8; ++k) {
                As[row][sg * 8 + k] = a[k];
                Ms[row][sg * 8 + k] = a[k] * f[k];
            }
        }
        __syncthreads();

        const int dbase = wv * 16;
        float acc1[16], acc2[16];
#pragma unroll
        for (int j = 0; j < 16; ++j) {
            acc1[j] = b1s[dbase + j];
            acc2[j] = b2s[dbase + j];
        }
#pragma unroll 8
        for (int k = 0; k < 64; ++k) {
            float a = As[lane][k];
            float m = Ms[lane][k];
            const float4* w1p = reinterpret_cast<const float4*>(&W1s[k * 64 + dbase]);
            const float4* w2p = reinterpret_cast<const float4*>(&W2s[k * 64 + dbase]);
#pragma unroll
            for (int q = 0; q < 4; ++q) {
                float4 w1 = w1p[q];
                float4 w2 = w2p[q];
                acc1[q * 4 + 0] += a * w1.x;
                acc1[q * 4 + 1] += a * w1.y;
                acc1[q * 4 + 2] += a * w1.z;
                acc1[q * 4 + 3] += a * w1.w;
                acc2[q * 4 + 0] += m * w2.x;
                acc2[q * 4 + 1] += m * w2.y;
                acc2[q * 4 + 2] += m * w2.z;
                acc2[q * 4 + 3] += m * w2.w;
            }
        }

        const int n = base + lane;
        if (n < NN) {
#pragma unroll
            for (int q = 0; q < 4; ++q) {
                float r[4];
#pragma unroll
                for (int j = 0; j < 4; ++j) {
                    float x1 = acc1[q * 4 + j];
                    float x2 = acc2[q * 4 + j];
                    x1 = x1 >= 0.f ? x1 : 0.2f * x1;
                    x2 = x2 >= 0.f ? x2 : 0.2f * x2;
                    r[j] = x1 + x2;
                }
                *reinterpret_cast<float4*>(&out[(size_t)n * D + dbase + q * 4]) =
                    make_float4(r[0], r[1], r[2], r[3]);
            }
        }
    }
}

extern "C" void kernel_launch(void* const* d_in, const int* in_sizes, int n_in,
                              void* d_out, int out_size, void* d_ws, size_t ws_size,
                              hipStream_t stream) {
    const int* rows = (const int*)d_in[0];
    const int* cols = (const int*)d_in[1];
    const float* vals = (const float*)d_in[2];
    const float* feat = (const float*)d_in[3];
    const float* W1 = (const float*)d_in[4];
    const float* b1 = (const float*)d_in[5];
    const float* W2 = (const float*)d_in[6];
    const float* b2 = (const float*)d_in[7];
    float* out = (float*)d_out;

    char* ws = (char*)d_ws;
    unsigned short* agg16 = (unsigned short*)(ws + OFF_AGG16);
    int* bh = (int*)(ws + OFF_BH);
    int* bsum = (int*)(ws + OFF_BS);
    int2* coarse = (int2*)(ws + OFF_COARSE);
    unsigned short* feat16 = (unsigned short*)(ws + OFF_F16);

    // feat -> bf16
    conv_k<<<(NN * D / 8 + 255) / 256, 256, 0, stream>>>(feat, feat16);

    // coarse radix: per-(bucket,block) hist -> exclusive scan (in-place) -> bin
    bhist_k<<<NB, 256, 0, stream>>>(rows, bh);
    scan1_k<<<NSB, 256, 0, stream>>>(bh, bsum);
    scan2_k<<<1, 256, 0, stream>>>(bsum);
    scan3_k<<<(NH + 255) / 256, 256, 0, stream>>>(bh, bsum);
    bin_k<<<NB, 256, 0, stream>>>(rows, cols, vals, bh, coarse);

    // per-bucket sort + register-accumulate gather (no f32 atomics anywhere)
    bgather_k<<<NBK, 256, 0, stream>>>(bh, coarse, feat16, agg16);

    // MLP
    const int ntiles = (NN + 63) / 64;
    mlp_k<<<ntiles, 256, 0, stream>>>(agg16, feat, W1, b1, W2, b2, out);
}

// Round 16
// 156.887 us; speedup vs baseline: 1.1191x; 1.1191x over previous
//
#include <hip/hip_runtime.h>

#define NN 100000
#define NE 1600000
#define D 64
#define NB 256                                 // binning blocks
#define EPB (NE / NB)                          // 6250 edges per bin block
#define BROWS 128                              // rows per bucket (bh granularity)
#define HROWS 64                               // rows per bgather block (half)
#define NBK ((NN + BROWS - 1) / BROWS)         // 782 buckets
#define NH (NBK * NB)                          // 200192 hist entries
#define SCAN_BLK 1024
#define NSB ((NH + SCAN_BLK - 1) / SCAN_BLK)   // 196
#define CAP 1536                               // per-half capacity (~16 sigma)

// ---------------- ws layout (bytes), total 39,201,792 (proven) -------------
// agg16  : [0, 12800000)             NN*D bf16
// bh     : [12800000, +800768)       NH int (hist -> in-place exclusive scan)
// bsum   : [13600768, +1024)         NSB int
// coarse : [13601792, +12800000)     NE int2 ((rowlocal<<17)|col, val-bits)
// feat16 : [26401792, +12800000)     NN*D bf16
static constexpr size_t OFF_AGG16  = 0;
static constexpr size_t OFF_BH     = 12800000;
static constexpr size_t OFF_BS     = 13600768;
static constexpr size_t OFF_COARSE = 13601792;
static constexpr size_t OFF_F16    = 26401792;

__device__ __forceinline__ unsigned short f32_to_bf16_rn(float x) {
    unsigned int u = __float_as_uint(x);
    u += 0x7FFFu + ((u >> 16) & 1u);  // round-to-nearest-even
    return (unsigned short)(u >> 16);
}
__device__ __forceinline__ float bf16_to_f32(unsigned int lo16) {
    return __uint_as_float(lo16 << 16);
}

// 0) feat f32 -> bf16 (8 elems/thread)
__global__ __launch_bounds__(256) void conv_k(const float* __restrict__ feat,
                                              unsigned short* __restrict__ feat16) {
    int i = blockIdx.x * blockDim.x + threadIdx.x;
    if (i >= NN * D / 8) return;
    const float4 f0 = *reinterpret_cast<const float4*>(&feat[i * 8]);
    const float4 f1 = *reinterpret_cast<const float4*>(&feat[i * 8 + 4]);
    uint4 o;
    o.x = f32_to_bf16_rn(f0.x) | ((unsigned int)f32_to_bf16_rn(f0.y) << 16);
    o.y = f32_to_bf16_rn(f0.z) | ((unsigned int)f32_to_bf16_rn(f0.w) << 16);
    o.z = f32_to_bf16_rn(f1.x) | ((unsigned int)f32_to_bf16_rn(f1.y) << 16);
    o.w = f32_to_bf16_rn(f1.z) | ((unsigned int)f32_to_bf16_rn(f1.w) << 16);
    *reinterpret_cast<uint4*>(&feat16[i * 8]) = o;
}

// 1) per-(bucket, block) histogram. bh layout bucket-major: bh[b*NB + blk]
__global__ __launch_bounds__(256) void bhist_k(const int* __restrict__ rows,
                                               int* __restrict__ bh) {
    __shared__ int h[NBK];
    for (int i = threadIdx.x; i < NBK; i += 256) h[i] = 0;
    __syncthreads();
    const int e0 = blockIdx.x * EPB;
    for (int e = e0 + threadIdx.x; e < e0 + EPB; e += 256)
        atomicAdd(&h[rows[e] >> 7], 1);
    __syncthreads();
    for (int i = threadIdx.x; i < NBK; i += 256) bh[i * NB + blockIdx.x] = h[i];
}

// 2a) per-1024-block exclusive scan over bh, IN-PLACE; block sums out
__global__ __launch_bounds__(256) void scan1_k(int* __restrict__ a,
                                               int* __restrict__ bsum) {
    __shared__ int tsum[256];
    const int base = blockIdx.x * SCAN_BLK + threadIdx.x * 4;
    int v[4];
    int s = 0;
#pragma unroll
    for (int i = 0; i < 4; ++i) {
        int idx = base + i;
        v[i] = (idx < NH) ? a[idx] : 0;
        s += v[i];
    }
    tsum[threadIdx.x] = s;
    __syncthreads();
    int x = s;
    for (int off = 1; off < 256; off <<= 1) {
        int y = (threadIdx.x >= off) ? tsum[threadIdx.x - off] : 0;
        __syncthreads();
        x += y;
        tsum[threadIdx.x] = x;
        __syncthreads();
    }
    int run = x - s;
#pragma unroll
    for (int i = 0; i < 4; ++i) {
        int idx = base + i;
        if (idx < NH) a[idx] = run;
        run += v[i];
    }
    if (threadIdx.x == 255) bsum[blockIdx.x] = x;
}

// 2b) exclusive scan of NSB (=196) block sums
__global__ void scan2_k(int* __restrict__ bsum) {
    __shared__ int s[256];
    int i = threadIdx.x;
    int v = (i < NSB) ? bsum[i] : 0;
    s[i] = v;
    __syncthreads();
    int x = v;
    for (int off = 1; off < 256; off <<= 1) {
        int y = (i >= off) ? s[i - off] : 0;
        __syncthreads();
        x += y;
        s[i] = x;
        __syncthreads();
    }
    if (i < NSB) bsum[i] = x - v;  // exclusive
}

// 2c) add block offsets
__global__ __launch_bounds__(256) void scan3_k(int* __restrict__ a,
                                               const int* __restrict__ bsum) {
    int i = blockIdx.x * blockDim.x + threadIdx.x;
    if (i < NH) a[i] += bsum[i >> 10];
}

// 3) bin edges into coarse buckets at exact (block,bucket) offsets.
//    256 blocks (R14 config: bin stayed under 40us; R15's 128 blocks = 4.7%
//    occupancy, 66-70us — binning grid must cover the CUs).
__global__ __launch_bounds__(256) void bin_k(const int* __restrict__ rows,
                                             const int* __restrict__ cols,
                                             const float* __restrict__ vals,
                                             const int* __restrict__ bh,
                                             int2* __restrict__ coarse) {
    __shared__ int cur[NBK];
    for (int i = threadIdx.x; i < NBK; i += 256) cur[i] = 0;
    __syncthreads();
    const int e0 = blockIdx.x * EPB;
    for (int e = e0 + threadIdx.x; e < e0 + EPB; e += 256) {
        int r = rows[e];
        int b = r >> 7;
        int pos = atomicAdd(&cur[b], 1);
        coarse[bh[b * NB + blockIdx.x] + pos] =
            make_int2(((r & 127) << 17) | cols[e], __float_as_int(vals[e]));
    }
}

// 4) per-half-bucket LDS counting-sort + register-accumulate gather.
//    Grid = 2*NBK (1564 blocks, vs R14's 782 at 26% occupancy): block
//    (b = blk>>1, h = blk&1) owns rows [b*128 + h*64, +64). Streams the
//    bucket's edges, filters its half, sorts in LDS (12.8 KB -> 8 blocks/CU),
//    then wave wv gathers rows [wv*16, +16) with 8 edges in flight.
__global__ __launch_bounds__(256) void bgather_k(const int* __restrict__ bh,
                                                 const int2* __restrict__ coarse,
                                                 const unsigned short* __restrict__ feat16,
                                                 unsigned short* __restrict__ agg16) {
    __shared__ int2 se[CAP];
    __shared__ int hist[HROWS];    // counts -> cursor base
    __shared__ int rsl[HROWS];     // inclusive scan
    const int blk = blockIdx.x;
    const int b = blk >> 1;
    const int h = blk & 1;
    const int start = bh[b * NB];
    const int end = (b == NBK - 1) ? NE : bh[(b + 1) * NB];

    const int tid = threadIdx.x;
    if (tid < HROWS) hist[tid] = 0;
    __syncthreads();
    for (int i = start + tid; i < end; i += 256) {
        int rl = ((unsigned)coarse[i].x) >> 17;             // 0..127
        if ((rl >> 6) == h) atomicAdd(&hist[rl & 63], 1);
    }
    __syncthreads();
    if (tid < HROWS) rsl[tid] = hist[tid];
    __syncthreads();
    for (int off = 1; off < HROWS; off <<= 1) {
        int y = 0;
        if (tid < HROWS && tid >= off) y = rsl[tid - off];
        __syncthreads();
        if (tid < HROWS) rsl[tid] += y;
        __syncthreads();
    }
    if (tid < HROWS) hist[tid] = rsl[tid] - hist[tid];      // cursor = row start
    __syncthreads();
    for (int i = start + tid; i < end; i += 256) {
        int2 ev = coarse[i];
        int rl = ((unsigned)ev.x) >> 17;
        if ((rl >> 6) == h) {
            int p = atomicAdd(&hist[rl & 63], 1);
            if (p < CAP) se[p] = ev;                        // 16-sigma guard
        }
    }
    __syncthreads();

    const int lane = tid & 63;
    const int wv = tid >> 6;
    const int g = lane >> 3;
    const int t = lane & 7;
    const int rowbase = b * BROWS + h * HROWS;

    for (int rl = wv * 16; rl < wv * 16 + 16; ++rl) {
        int r0 = (rl == 0) ? 0 : rsl[rl - 1];
        int r1 = rsl[rl];
        if (r0 > CAP) r0 = CAP;
        if (r1 > CAP) r1 = CAP;
        float acc[8];
#pragma unroll
        for (int k = 0; k < 8; ++k) acc[k] = 0.f;
        for (int base2 = r0; base2 < r1; base2 += 8) {
            int m = r1 - base2;
            if (m > 8) m = 8;
            int2 ev = se[base2 + (g < m ? g : 0)];   // 8-lane broadcast per group
            float vj = (g < m) ? __int_as_float(ev.y) : 0.f;
            int cj = ev.x & 0x1FFFF;
            const uint4 f =
                *reinterpret_cast<const uint4*>(&feat16[(size_t)cj * D + (t << 3)]);
            acc[0] += vj * bf16_to_f32(f.x & 0xffffu);
            acc[1] += vj * bf16_to_f32(f.x >> 16);
            acc[2] += vj * bf16_to_f32(f.y & 0xffffu);
            acc[3] += vj * bf16_to_f32(f.y >> 16);
            acc[4] += vj * bf16_to_f32(f.z & 0xffffu);
            acc[5] += vj * bf16_to_f32(f.z >> 16);
            acc[6] += vj * bf16_to_f32(f.w & 0xffffu);
            acc[7] += vj * bf16_to_f32(f.w >> 16);
        }
#pragma unroll
        for (int off = 8; off <= 32; off <<= 1) {
#pragma unroll
            for (int k = 0; k < 8; ++k) acc[k] += __shfl_xor(acc[k], off);
        }
        const int r = rowbase + rl;
        if (lane < 8 && r < NN) {
            uint4 o;
            o.x = f32_to_bf16_rn(acc[0]) | ((unsigned int)f32_to_bf16_rn(acc[1]) << 16);
            o.y = f32_to_bf16_rn(acc[2]) | ((unsigned int)f32_to_bf16_rn(acc[3]) << 16);
            o.z = f32_to_bf16_rn(acc[4]) | ((unsigned int)f32_to_bf16_rn(acc[5]) << 16);
            o.w = f32_to_bf16_rn(acc[6]) | ((unsigned int)f32_to_bf16_rn(acc[7]) << 16);
            *reinterpret_cast<uint4*>(&agg16[(size_t)r * D + (t << 3)]) = o;
        }
    }
}

// 5) out = leaky(agg@W1+b1) + leaky((agg*feat)@W2+b2); agg in bf16
__global__ __launch_bounds__(256) void mlp_k(const unsigned short* __restrict__ agg16,
                                             const float* __restrict__ feat,
                                             const float* __restrict__ W1,
                                             const float* __restrict__ b1,
                                             const float* __restrict__ W2,
                                             const float* __restrict__ b2,
                                             float* __restrict__ out) {
    __shared__ float W1s[64 * 64];
    __shared__ float W2s[64 * 64];
    __shared__ float b1s[64], b2s[64];
    __shared__ float As[64][65];
    __shared__ float Ms[64][65];

    for (int i = threadIdx.x; i < 4096; i += 256) {
        W1s[i] = W1[i];
        W2s[i] = W2[i];
    }
    if (threadIdx.x < 64) {
        b1s[threadIdx.x] = b1[threadIdx.x];
        b2s[threadIdx.x] = b2[threadIdx.x];
    }

    const int wv = threadIdx.x >> 6;
    const int lane = threadIdx.x & 63;
    const int ntiles = (NN + 63) / 64;

    for (int t = blockIdx.x; t < ntiles; t += gridDim.x) {
        const int base = t * 64;
        __syncthreads();
        for (int i = threadIdx.x; i < 512; i += 256) {
            int row = i >> 3;
            int sg = i & 7;
            int n = base + row;
            uint4 a16 = make_uint4(0, 0, 0, 0);
            float4 f0 = make_float4(0.f, 0.f, 0.f, 0.f);
            float4 f1 = make_float4(0.f, 0.f, 0.f, 0.f);
            if (n < NN) {
                a16 = *reinterpret_cast<const uint4*>(&agg16[(size_t)n * D + sg * 8]);
                f0 = *reinterpret_cast<const float4*>(&feat[(size_t)n * D + sg * 8]);
                f1 = *reinterpret_cast<const float4*>(&feat[(size_t)n * D + sg * 8 + 4]);
            }
            float a[8];
            a[0] = bf16_to_f32(a16.x & 0xffffu);
            a[1] = bf16_to_f32(a16.x >> 16);
            a[2] = bf16_to_f32(a16.y & 0xffffu);
            a[3] = bf16_to_f32(a16.y >> 16);
            a[4] = bf16_to_f32(a16.z & 0xffffu);
            a[5] = bf16_to_f32(a16.z >> 16);
            a[6] = bf16_to_f32(a16.w & 0xffffu);
            a[7] = bf16_to_f32(a16.w >> 16);
            float f[8] = {f0.x, f0.y, f0.z, f0.w, f1.x, f1.y, f1.z, f1.w};
#pragma unroll
            for (int k = 0; k < 8; ++k) {
                As[row][sg * 8 + k] = a[k];
                Ms[row][sg * 8 + k] = a[k] * f[k];
            }
        }
        __syncthreads();

        const int dbase = wv * 16;
        float acc1[16], acc2[16];
#pragma unroll
        for (int j = 0; j < 16; ++j) {
            acc1[j] = b1s[dbase + j];
            acc2[j] = b2s[dbase + j];
        }
#pragma unroll 8
        for (int k = 0; k < 64; ++k) {
            float a = As[lane][k];
            float m = Ms[lane][k];
            const float4* w1p = reinterpret_cast<const float4*>(&W1s[k * 64 + dbase]);
            const float4* w2p = reinterpret_cast<const float4*>(&W2s[k * 64 + dbase]);
#pragma unroll
            for (int q = 0; q < 4; ++q) {
                float4 w1 = w1p[q];
                float4 w2 = w2p[q];
                acc1[q * 4 + 0] += a * w1.x;
                acc1[q * 4 + 1] += a * w1.y;
                acc1[q * 4 + 2] += a * w1.z;
                acc1[q * 4 + 3] += a * w1.w;
                acc2[q * 4 + 0] += m * w2.x;
                acc2[q * 4 + 1] += m * w2.y;
                acc2[q * 4 + 2] += m * w2.z;
                acc2[q * 4 + 3] += m * w2.w;
            }
        }

        const int n = base + lane;
        if (n < NN) {
#pragma unroll
            for (int q = 0; q < 4; ++q) {
                float r[4];
#pragma unroll
                for (int j = 0; j < 4; ++j) {
                    float x1 = acc1[q * 4 + j];
                    float x2 = acc2[q * 4 + j];
                    x1 = x1 >= 0.f ? x1 : 0.2f * x1;
                    x2 = x2 >= 0.f ? x2 : 0.2f * x2;
                    r[j] = x1 + x2;
                }
                *reinterpret_cast<float4*>(&out[(size_t)n * D + dbase + q * 4]) =
                    make_float4(r[0], r[1], r[2], r[3]);
            }
        }
    }
}

extern "C" void kernel_launch(void* const* d_in, const int* in_sizes, int n_in,
                              void* d_out, int out_size, void* d_ws, size_t ws_size,
                              hipStream_t stream) {
    const int* rows = (const int*)d_in[0];
    const int* cols = (const int*)d_in[1];
    const float* vals = (const float*)d_in[2];
    const float* feat = (const float*)d_in[3];
    const float* W1 = (const float*)d_in[4];
    const float* b1 = (const float*)d_in[5];
    const float* W2 = (const float*)d_in[6];
    const float* b2 = (const float*)d_in[7];
    float* out = (float*)d_out;

    char* ws = (char*)d_ws;
    unsigned short* agg16 = (unsigned short*)(ws + OFF_AGG16);
    int* bh = (int*)(ws + OFF_BH);
    int* bsum = (int*)(ws + OFF_BS);
    int2* coarse = (int2*)(ws + OFF_COARSE);
    unsigned short* feat16 = (unsigned short*)(ws + OFF_F16);

    // feat -> bf16
    conv_k<<<(NN * D / 8 + 255) / 256, 256, 0, stream>>>(feat, feat16);

    // coarse radix: per-(bucket,block) hist -> exclusive scan (in-place) -> bin
    bhist_k<<<NB, 256, 0, stream>>>(rows, bh);
    scan1_k<<<NSB, 256, 0, stream>>>(bh, bsum);
    scan2_k<<<1, 256, 0, stream>>>(bsum);
    scan3_k<<<(NH + 255) / 256, 256, 0, stream>>>(bh, bsum);
    bin_k<<<NB, 256, 0, stream>>>(rows, cols, vals, bh, coarse);

    // per-half-bucket sort + register-accumulate gather (2 blocks per bucket)
    bgather_k<<<NBK * 2, 256, 0, stream>>>(bh, coarse, feat16, agg16);

    // MLP
    const int ntiles = (NN + 63) / 64;
    mlp_k<<<ntiles, 256, 0, stream>>>(agg16, feat, W1, b1, W2, b2, out);
}

// Round 17
// 116.731 us; speedup vs baseline: 1.5041x; 1.3440x over previous
//
#include <hip/hip_runtime.h>

#define NN 100000
#define NE 1600000
#define D 64
#define NB 256                                 // binning blocks
#define EPB (NE / NB)                          // 6250 edges per bin block
#define BROWS 128                               // rows per bucket (bh granularity)
#define HROWS 64                               // rows per bgather block (half)
#define NBK ((NN + BROWS - 1) / BROWS)         // 782 buckets
#define NH (NBK * NB)                          // 200192 hist entries
#define SCAN_BLK 1024
#define NSB ((NH + SCAN_BLK - 1) / SCAN_BLK)   // 196
#define CAP 1536                               // per-half capacity (~16 sigma)
#define WT_LD 72                               // padded K leading dim (144B rows)

// ---------------- ws layout (bytes), total 39,201,792 (proven) -------------
static constexpr size_t OFF_AGG16  = 0;
static constexpr size_t OFF_BH     = 12800000;
static constexpr size_t OFF_BS     = 13600768;
static constexpr size_t OFF_COARSE = 13601792;
static constexpr size_t OFF_F16    = 26401792;

typedef short bf16x8 __attribute__((ext_vector_type(8)));
typedef float f32x4 __attribute__((ext_vector_type(4)));

__device__ __forceinline__ unsigned short f32_to_bf16_rn(float x) {
    unsigned int u = __float_as_uint(x);
    u += 0x7FFFu + ((u >> 16) & 1u);  // round-to-nearest-even
    return (unsigned short)(u >> 16);
}
__device__ __forceinline__ float bf16_to_f32(unsigned int lo16) {
    return __uint_as_float(lo16 << 16);
}

// 0) feat f32 -> bf16 (8 elems/thread)
__global__ __launch_bounds__(256) void conv_k(const float* __restrict__ feat,
                                              unsigned short* __restrict__ feat16) {
    int i = blockIdx.x * blockDim.x + threadIdx.x;
    if (i >= NN * D / 8) return;
    const float4 f0 = *reinterpret_cast<const float4*>(&feat[i * 8]);
    const float4 f1 = *reinterpret_cast<const float4*>(&feat[i * 8 + 4]);
    uint4 o;
    o.x = f32_to_bf16_rn(f0.x) | ((unsigned int)f32_to_bf16_rn(f0.y) << 16);
    o.y = f32_to_bf16_rn(f0.z) | ((unsigned int)f32_to_bf16_rn(f0.w) << 16);
    o.z = f32_to_bf16_rn(f1.x) | ((unsigned int)f32_to_bf16_rn(f1.y) << 16);
    o.w = f32_to_bf16_rn(f1.z) | ((unsigned int)f32_to_bf16_rn(f1.w) << 16);
    *reinterpret_cast<uint4*>(&feat16[i * 8]) = o;
}

// 1) per-(bucket, block) histogram. bh layout bucket-major: bh[b*NB + blk]
__global__ __launch_bounds__(256) void bhist_k(const int* __restrict__ rows,
                                               int* __restrict__ bh) {
    __shared__ int h[NBK];
    for (int i = threadIdx.x; i < NBK; i += 256) h[i] = 0;
    __syncthreads();
    const int e0 = blockIdx.x * EPB;
    for (int e = e0 + threadIdx.x; e < e0 + EPB; e += 256)
        atomicAdd(&h[rows[e] >> 7], 1);
    __syncthreads();
    for (int i = threadIdx.x; i < NBK; i += 256) bh[i * NB + blockIdx.x] = h[i];
}

// 2a) per-1024-block exclusive scan over bh, IN-PLACE; block sums out
__global__ __launch_bounds__(256) void scan1_k(int* __restrict__ a,
                                               int* __restrict__ bsum) {
    __shared__ int tsum[256];
    const int base = blockIdx.x * SCAN_BLK + threadIdx.x * 4;
    int v[4];
    int s = 0;
#pragma unroll
    for (int i = 0; i < 4; ++i) {
        int idx = base + i;
        v[i] = (idx < NH) ? a[idx] : 0;
        s += v[i];
    }
    tsum[threadIdx.x] = s;
    __syncthreads();
    int x = s;
    for (int off = 1; off < 256; off <<= 1) {
        int y = (threadIdx.x >= off) ? tsum[threadIdx.x - off] : 0;
        __syncthreads();
        x += y;
        tsum[threadIdx.x] = x;
        __syncthreads();
    }
    int run = x - s;
#pragma unroll
    for (int i = 0; i < 4; ++i) {
        int idx = base + i;
        if (idx < NH) a[idx] = run;
        run += v[i];
    }
    if (threadIdx.x == 255) bsum[blockIdx.x] = x;
}

// 2b) exclusive scan of NSB (=196) block sums
__global__ void scan2_k(int* __restrict__ bsum) {
    __shared__ int s[256];
    int i = threadIdx.x;
    int v = (i < NSB) ? bsum[i] : 0;
    s[i] = v;
    __syncthreads();
    int x = v;
    for (int off = 1; off < 256; off <<= 1) {
        int y = (i >= off) ? s[i - off] : 0;
        __syncthreads();
        x += y;
        s[i] = x;
        __syncthreads();
    }
    if (i < NSB) bsum[i] = x - v;  // exclusive
}

// 2c) add block offsets
__global__ __launch_bounds__(256) void scan3_k(int* __restrict__ a,
                                               const int* __restrict__ bsum) {
    int i = blockIdx.x * blockDim.x + threadIdx.x;
    if (i < NH) a[i] += bsum[i >> 10];
}

// 3) bin edges into coarse buckets at exact (block,bucket) offsets.
__global__ __launch_bounds__(256) void bin_k(const int* __restrict__ rows,
                                             const int* __restrict__ cols,
                                             const float* __restrict__ vals,
                                             const int* __restrict__ bh,
                                             int2* __restrict__ coarse) {
    __shared__ int cur[NBK];
    for (int i = threadIdx.x; i < NBK; i += 256) cur[i] = 0;
    __syncthreads();
    const int e0 = blockIdx.x * EPB;
    for (int e = e0 + threadIdx.x; e < e0 + EPB; e += 256) {
        int r = rows[e];
        int b = r >> 7;
        int pos = atomicAdd(&cur[b], 1);
        coarse[bh[b * NB + blockIdx.x] + pos] =
            make_int2(((r & 127) << 17) | cols[e], __float_as_int(vals[e]));
    }
}

// 4) per-half-bucket LDS counting-sort + register-accumulate gather.
__global__ __launch_bounds__(256) void bgather_k(const int* __restrict__ bh,
                                                 const int2* __restrict__ coarse,
                                                 const unsigned short* __restrict__ feat16,
                                                 unsigned short* __restrict__ agg16) {
    __shared__ int2 se[CAP];
    __shared__ int hist[HROWS];    // counts -> cursor base
    __shared__ int rsl[HROWS];     // inclusive scan
    const int blk = blockIdx.x;
    const int b = blk >> 1;
    const int h = blk & 1;
    const int start = bh[b * NB];
    const int end = (b == NBK - 1) ? NE : bh[(b + 1) * NB];

    const int tid = threadIdx.x;
    if (tid < HROWS) hist[tid] = 0;
    __syncthreads();
    for (int i = start + tid; i < end; i += 256) {
        int rl = ((unsigned)coarse[i].x) >> 17;             // 0..127
        if ((rl >> 6) == h) atomicAdd(&hist[rl & 63], 1);
    }
    __syncthreads();
    if (tid < HROWS) rsl[tid] = hist[tid];
    __syncthreads();
    for (int off = 1; off < HROWS; off <<= 1) {
        int y = 0;
        if (tid < HROWS && tid >= off) y = rsl[tid - off];
        __syncthreads();
        if (tid < HROWS) rsl[tid] += y;
        __syncthreads();
    }
    if (tid < HROWS) hist[tid] = rsl[tid] - hist[tid];      // cursor = row start
    __syncthreads();
    for (int i = start + tid; i < end; i += 256) {
        int2 ev = coarse[i];
        int rl = ((unsigned)ev.x) >> 17;
        if ((rl >> 6) == h) {
            int p = atomicAdd(&hist[rl & 63], 1);
            if (p < CAP) se[p] = ev;                        // 16-sigma guard
        }
    }
    __syncthreads();

    const int lane = tid & 63;
    const int wv = tid >> 6;
    const int g = lane >> 3;
    const int t = lane & 7;
    const int rowbase = b * BROWS + h * HROWS;

    for (int rl = wv * 16; rl < wv * 16 + 16; ++rl) {
        int r0 = (rl == 0) ? 0 : rsl[rl - 1];
        int r1 = rsl[rl];
        if (r0 > CAP) r0 = CAP;
        if (r1 > CAP) r1 = CAP;
        float acc[8];
#pragma unroll
        for (int k = 0; k < 8; ++k) acc[k] = 0.f;
        for (int base2 = r0; base2 < r1; base2 += 8) {
            int m = r1 - base2;
            if (m > 8) m = 8;
            int2 ev = se[base2 + (g < m ? g : 0)];   // 8-lane broadcast per group
            float vj = (g < m) ? __int_as_float(ev.y) : 0.f;
            int cj = ev.x & 0x1FFFF;
            const uint4 f =
                *reinterpret_cast<const uint4*>(&feat16[(size_t)cj * D + (t << 3)]);
            acc[0] += vj * bf16_to_f32(f.x & 0xffffu);
            acc[1] += vj * bf16_to_f32(f.x >> 16);
            acc[2] += vj * bf16_to_f32(f.y & 0xffffu);
            acc[3] += vj * bf16_to_f32(f.y >> 16);
            acc[4] += vj * bf16_to_f32(f.z & 0xffffu);
            acc[5] += vj * bf16_to_f32(f.z >> 16);
            acc[6] += vj * bf16_to_f32(f.w & 0xffffu);
            acc[7] += vj * bf16_to_f32(f.w >> 16);
        }
#pragma unroll
        for (int off = 8; off <= 32; off <<= 1) {
#pragma unroll
            for (int k = 0; k < 8; ++k) acc[k] += __shfl_xor(acc[k], off);
        }
        const int r = rowbase + rl;
        if (lane < 8 && r < NN) {
            uint4 o;
            o.x = f32_to_bf16_rn(acc[0]) | ((unsigned int)f32_to_bf16_rn(acc[1]) << 16);
            o.y = f32_to_bf16_rn(acc[2]) | ((unsigned int)f32_to_bf16_rn(acc[3]) << 16);
            o.z = f32_to_bf16_rn(acc[4]) | ((unsigned int)f32_to_bf16_rn(acc[5]) << 16);
            o.w = f32_to_bf16_rn(acc[6]) | ((unsigned int)f32_to_bf16_rn(acc[7]) << 16);
            *reinterpret_cast<uint4*>(&agg16[(size_t)r * D + (t << 3)]) = o;
        }
    }
}

// 5) MFMA MLP: out = leaky(agg@W1+b1) + leaky((agg*feat)@W2+b2).
//    Block = 64-node tile, 4 waves; wave wv computes rows [wv*16,+16) x 64 cols
//    via mfma_f32_16x16x32_bf16 (2 K-steps x 4 N-blocks x 2 GEMMs = 16 MFMA).
//    A-frags load direct from global (lane l: row l&15, k = (l>>4)*8, 16B);
//    W1/W2 staged once as transposed bf16 Wt[n][k], K padded to 72 (144B rows:
//    16B-aligned ds_read_b128, 2-way banks = free). Product frag in-register.
//    C/D layout (verified m89): row=(lane>>4)*4+j, col=lane&15.
__global__ __launch_bounds__(256) void mlp_k(const unsigned short* __restrict__ agg16,
                                             const unsigned short* __restrict__ feat16,
                                             const float* __restrict__ W1,
                                             const float* __restrict__ b1,
                                             const float* __restrict__ W2,
                                             const float* __restrict__ b2,
                                             float* __restrict__ out) {
    __shared__ unsigned short W1t[64 * WT_LD];
    __shared__ unsigned short W2t[64 * WT_LD];
    for (int idx = threadIdx.x; idx < 4096; idx += 256) {
        int k = idx >> 6, n = idx & 63;           // consecutive tid -> consecutive n
        W1t[n * WT_LD + k] = f32_to_bf16_rn(W1[idx]);
        W2t[n * WT_LD + k] = f32_to_bf16_rn(W2[idx]);
    }
    __syncthreads();

    const int lane = threadIdx.x & 63;
    const int wv = threadIdx.x >> 6;
    const int lm = lane & 15;       // fragment M/N index
    const int lk = lane >> 4;       // fragment K group (0..3)
    const int rowA = blockIdx.x * 64 + wv * 16 + lm;
    const bool valid = rowA < NN;
    const size_t abase = (size_t)rowA * D;

    f32x4 acc1[4], acc2[4];
#pragma unroll
    for (int nb = 0; nb < 4; ++nb) {
        acc1[nb] = (f32x4){0.f, 0.f, 0.f, 0.f};
        acc2[nb] = (f32x4){0.f, 0.f, 0.f, 0.f};
    }

    union U { uint4 u; bf16x8 v; };

#pragma unroll
    for (int kk = 0; kk < 2; ++kk) {
        const int k0 = kk * 32 + lk * 8;
        U ua, uf, um;
        ua.u = make_uint4(0, 0, 0, 0);
        uf.u = make_uint4(0, 0, 0, 0);
        if (valid) {
            ua.u = *reinterpret_cast<const uint4*>(&agg16[abase + k0]);
            uf.u = *reinterpret_cast<const uint4*>(&feat16[abase + k0]);
        }
        // product fragment m = a*f, rounded to bf16
        {
            const unsigned int* au = &ua.u.x;
            const unsigned int* fu = &uf.u.x;
            unsigned int* mu = &um.u.x;
#pragma unroll
            for (int q = 0; q < 4; ++q) {
                float lo = bf16_to_f32(au[q] & 0xffffu) * bf16_to_f32(fu[q] & 0xffffu);
                float hi = bf16_to_f32(au[q] >> 16) * bf16_to_f32(fu[q] >> 16);
                mu[q] = f32_to_bf16_rn(lo) | ((unsigned int)f32_to_bf16_rn(hi) << 16);
            }
        }
#pragma unroll
        for (int nb = 0; nb < 4; ++nb) {
            U b1f, b2f;
            b1f.v = *reinterpret_cast<const bf16x8*>(&W1t[(nb * 16 + lm) * WT_LD + k0]);
            b2f.v = *reinterpret_cast<const bf16x8*>(&W2t[(nb * 16 + lm) * WT_LD + k0]);
            acc1[nb] = __builtin_amdgcn_mfma_f32_16x16x32_bf16(ua.v, b1f.v, acc1[nb], 0, 0, 0);
            acc2[nb] = __builtin_amdgcn_mfma_f32_16x16x32_bf16(um.v, b2f.v, acc2[nb], 0, 0, 0);
        }
    }

#pragma unroll
    for (int nb = 0; nb < 4; ++nb) {
        const int col = nb * 16 + lm;
        const float bb1 = b1[col];
        const float bb2 = b2[col];
#pragma unroll
        for (int j = 0; j < 4; ++j) {
            const int row = blockIdx.x * 64 + wv * 16 + lk * 4 + j;
            if (row < NN) {
                float x1 = acc1[nb][j] + bb1;
                float x2 = acc2[nb][j] + bb2;
                x1 = x1 >= 0.f ? x1 : 0.2f * x1;
                x2 = x2 >= 0.f ? x2 : 0.2f * x2;
                out[(size_t)row * D + col] = x1 + x2;
            }
        }
    }
}

extern "C" void kernel_launch(void* const* d_in, const int* in_sizes, int n_in,
                              void* d_out, int out_size, void* d_ws, size_t ws_size,
                              hipStream_t stream) {
    const int* rows = (const int*)d_in[0];
    const int* cols = (const int*)d_in[1];
    const float* vals = (const float*)d_in[2];
    const float* feat = (const float*)d_in[3];
    const float* W1 = (const float*)d_in[4];
    const float* b1 = (const float*)d_in[5];
    const float* W2 = (const float*)d_in[6];
    const float* b2 = (const float*)d_in[7];
    float* out = (float*)d_out;

    char* ws = (char*)d_ws;
    unsigned short* agg16 = (unsigned short*)(ws + OFF_AGG16);
    int* bh = (int*)(ws + OFF_BH);
    int* bsum = (int*)(ws + OFF_BS);
    int2* coarse = (int2*)(ws + OFF_COARSE);
    unsigned short* feat16 = (unsigned short*)(ws + OFF_F16);

    // feat -> bf16
    conv_k<<<(NN * D / 8 + 255) / 256, 256, 0, stream>>>(feat, feat16);

    // coarse radix: per-(bucket,block) hist -> exclusive scan (in-place) -> bin
    bhist_k<<<NB, 256, 0, stream>>>(rows, bh);
    scan1_k<<<NSB, 256, 0, stream>>>(bh, bsum);
    scan2_k<<<1, 256, 0, stream>>>(bsum);
    scan3_k<<<(NH + 255) / 256, 256, 0, stream>>>(bh, bsum);
    bin_k<<<NB, 256, 0, stream>>>(rows, cols, vals, bh, coarse);

    // per-half-bucket sort + register-accumulate gather (2 blocks per bucket)
    bgather_k<<<NBK * 2, 256, 0, stream>>>(bh, coarse, feat16, agg16);

    // MFMA MLP
    const int ntiles = (NN + 63) / 64;
    mlp_k<<<ntiles, 256, 0, stream>>>(agg16, feat16, W1, b1, W2, b2, out);
}